// Round 13
// baseline (437.126 us; speedup 1.0000x reference)
//
#include <hip/hip_runtime.h>
#include <hip/hip_fp16.h>

#define N_NODES 50000
#define N_EDGES 600000
#define D_IN 128
#define D_OUT 256
#define CAP 64          // bucket capacity per node (Poisson(12): P(deg>=48)~5e-14)

typedef __attribute__((ext_vector_type(8))) short short8v;
typedef __attribute__((ext_vector_type(4))) float float4v;

#define NB_CONVH 1563   // 256 thr * 16 f32 = 4096 elems/block
#define NB_CONVW 16     // 256 thr * 8 elems
#define NB_ZERO  49     // fallback prep: 12500 int4 / 256
#define NUNITS   782    // gemm 64-row units

__device__ inline unsigned bfbits(float f) {
    unsigned u = __float_as_uint(f);
    return (u + 0x7FFFu + ((u >> 16) & 1u)) >> 16;   // RNE f32 -> bf16 bits
}
__device__ inline unsigned pack2(float lo, float hi) {
    return bfbits(lo) | (bfbits(hi) << 16);
}
__device__ inline float w16(unsigned p) {
    return __half2float(__ushort_as_half((unsigned short)(p >> 16)));
}
__device__ inline void fma8(const uint4 v, const float w, float* a) {
    a[0] = fmaf(w, __uint_as_float(v.x << 16), a[0]);
    a[1] = fmaf(w, __uint_as_float(v.x & 0xFFFF0000u), a[1]);
    a[2] = fmaf(w, __uint_as_float(v.y << 16), a[2]);
    a[3] = fmaf(w, __uint_as_float(v.y & 0xFFFF0000u), a[3]);
    a[4] = fmaf(w, __uint_as_float(v.z << 16), a[4]);
    a[5] = fmaf(w, __uint_as_float(v.z & 0xFFFF0000u), a[5]);
    a[6] = fmaf(w, __uint_as_float(v.w << 16), a[6]);
    a[7] = fmaf(w, __uint_as_float(v.w & 0xFFFF0000u), a[7]);
}

// ---- device-scope grid barrier (all blocks co-resident by construction) ----
__device__ inline void grid_barrier(int* bar, int slot, int nblk) {
    __syncthreads();
    if (threadIdx.x == 0) {
        __threadfence();   // release: make this block's writes device-visible
        __hip_atomic_fetch_add(&bar[slot], 1, __ATOMIC_ACQ_REL,
                               __HIP_MEMORY_SCOPE_AGENT);
        long spins = 0;
        while (__hip_atomic_load(&bar[slot], __ATOMIC_ACQUIRE,
                                 __HIP_MEMORY_SCOPE_AGENT) < nblk) {
            __builtin_amdgcn_s_sleep(2);
            if (++spins > (1L << 31)) break;   // safety valve vs infinite hang
        }
    }
    __syncthreads();
}

// ---------- init: zero cursor + barrier slots ----------
__global__ __launch_bounds__(256)
void init_zero(int4* __restrict__ cursor4, int* __restrict__ bar) {
    const int i = blockIdx.x * 256 + threadIdx.x;
    if (i < N_NODES / 4) cursor4[i] = make_int4(0, 0, 0, 0);
    if (blockIdx.x == 0 && threadIdx.x < 8) bar[threadIdx.x] = 0;
}

// ---------- persistent fused kernel: {bucket|convH|convW} -> gather -> gemm --
__global__ __launch_bounds__(256, 8)
void sage_persist(const float* __restrict__ h, unsigned short* __restrict__ hb,
                  const float* __restrict__ W, unsigned short* __restrict__ wt,
                  int* __restrict__ cursor,
                  const int* __restrict__ esrc, const int* __restrict__ edst,
                  const float* __restrict__ ew, unsigned* __restrict__ bkt,
                  unsigned short* __restrict__ xb, float* __restrict__ out,
                  int* __restrict__ bar, int nblk) {
    const int t = threadIdx.x;
    const int wv = t >> 6;
    const int lane = t & 63;
    const int bid0 = blockIdx.x;

    // ---- Phase A: bucket fill (grid-stride edges; cursor zeroed by init) ----
    for (int e = bid0 * 256 + t; e < N_EDGES; e += nblk * 256) {
        const int d = edst[e];
        const unsigned entry =
            ((unsigned)__half_as_ushort(__float2half(ew[e])) << 16) | (unsigned)esrc[e];
        const int p = atomicAdd(&cursor[d], 1);
        if (p < CAP) bkt[(size_t)d * CAP + p] = entry;
    }
    // ---- Phase B: h -> bf16 (independent of A; overlaps other blocks' A) ----
    for (int b = bid0; b < NB_CONVH; b += nblk) {
        const size_t idx0 = ((size_t)b * 256 + t) * 16;
        if (idx0 < (size_t)N_NODES * D_IN) {
            float4 a = *reinterpret_cast<const float4*>(h + idx0);
            float4 bb = *reinterpret_cast<const float4*>(h + idx0 + 4);
            float4 c = *reinterpret_cast<const float4*>(h + idx0 + 8);
            float4 d = *reinterpret_cast<const float4*>(h + idx0 + 12);
            uint4 o1, o2;
            o1.x = pack2(a.x, a.y);  o1.y = pack2(a.z, a.w);
            o1.z = pack2(bb.x, bb.y); o1.w = pack2(bb.z, bb.w);
            o2.x = pack2(c.x, c.y);  o2.y = pack2(c.z, c.w);
            o2.z = pack2(d.x, d.y);  o2.w = pack2(d.z, d.w);
            *reinterpret_cast<uint4*>(hb + idx0) = o1;
            *reinterpret_cast<uint4*>(hb + idx0 + 8) = o2;
        }
    }
    // ---- Phase C: W -> Wt bf16 ----
    for (int b = bid0; b < NB_CONVW; b += nblk) {
        const int tid = b * 256 + t;
        const int n = tid >> 4;
        const int k0 = (tid & 15) * 8;
        uint4 o;
        o.x = pack2(W[(size_t)(k0 + 0) * D_OUT + n], W[(size_t)(k0 + 1) * D_OUT + n]);
        o.y = pack2(W[(size_t)(k0 + 2) * D_OUT + n], W[(size_t)(k0 + 3) * D_OUT + n]);
        o.z = pack2(W[(size_t)(k0 + 4) * D_OUT + n], W[(size_t)(k0 + 5) * D_OUT + n]);
        o.w = pack2(W[(size_t)(k0 + 6) * D_OUT + n], W[(size_t)(k0 + 7) * D_OUT + n]);
        *reinterpret_cast<uint4*>(wt + (size_t)n * D_IN + k0) = o;
    }

    grid_barrier(bar, 0, nblk);

    // ---- Phase D: gather-reduce, 1 node/wave (grid-stride waves) ----
    {
        const int q  = lane >> 4;
        const int sl = lane & 15;
        for (int n = bid0 * 4 + wv; n < N_NODES; n += nblk * 4) {
            const int cnt = min(cursor[n], CAP);
            float acc0[8] = {0.f, 0.f, 0.f, 0.f, 0.f, 0.f, 0.f, 0.f};
            float acc1[8] = {0.f, 0.f, 0.f, 0.f, 0.f, 0.f, 0.f, 0.f};
            const unsigned ent = bkt[(size_t)n * CAP + lane];   // 256B wave load
            int j = 0;
            for (; j + 8 <= cnt; j += 8) {
                const unsigned pa = __shfl(ent, j + q, 64);
                const unsigned pb = __shfl(ent, j + 4 + q, 64);
                const uint4 va = *reinterpret_cast<const uint4*>(
                    hb + (size_t)(pa & 0xFFFFu) * D_IN + sl * 8);
                const uint4 vb = *reinterpret_cast<const uint4*>(
                    hb + (size_t)(pb & 0xFFFFu) * D_IN + sl * 8);
                fma8(va, w16(pa), acc0);
                fma8(vb, w16(pb), acc1);
            }
            for (; j < cnt; j += 4) {
                const int idx = j + q;
                const bool act = idx < cnt;
                const unsigned pr = __shfl(ent, act ? idx : 0, 64);
                const unsigned p = act ? pr : 0u;
                const uint4 v = *reinterpret_cast<const uint4*>(
                    hb + (size_t)(p & 0xFFFFu) * D_IN + sl * 8);
                const float w = act ? w16(p) : 0.f;
                fma8(v, w, acc0);
            }
            float s[8];
            #pragma unroll
            for (int k = 0; k < 8; ++k) s[k] = acc0[k] + acc1[k];
            #pragma unroll
            for (int k = 0; k < 8; ++k) s[k] += __shfl_xor(s[k], 16, 64);
            #pragma unroll
            for (int k = 0; k < 8; ++k) s[k] += __shfl_xor(s[k], 32, 64);
            if (q == 0) {
                uint4 o;
                o.x = pack2(s[0], s[1]);
                o.y = pack2(s[2], s[3]);
                o.z = pack2(s[4], s[5]);
                o.w = pack2(s[6], s[7]);
                *reinterpret_cast<uint4*>(xb + (size_t)n * D_IN + sl * 8) = o;
            }
        }
    }

    grid_barrier(bar, 1, nblk);

    // ---- Phase E: gemm out = relu(xb @ wt^T) (grid-stride 64-row units) ----
    {
        const int g = lane >> 4;
        const int r = lane & 15;
        for (int u = bid0; u < NUNITS; u += nblk) {
            const int row0 = u * 64 + wv * 16;
            if (row0 >= N_NODES) continue;
            short8v a[4];
            const unsigned short* arow = xb + (size_t)(row0 + r) * D_IN + g * 8;
            #pragma unroll
            for (int s = 0; s < 4; ++s)
                a[s] = *reinterpret_cast<const short8v*>(arow + 32 * s);
            #pragma unroll
            for (int t2 = 0; t2 < 16; ++t2) {
                const unsigned short* brow = wt + (size_t)(t2 * 16 + r) * D_IN + g * 8;
                float4v acc = {0.f, 0.f, 0.f, 0.f};
                #pragma unroll
                for (int s = 0; s < 4; ++s) {
                    short8v b = *reinterpret_cast<const short8v*>(brow + 32 * s);
                    acc = __builtin_amdgcn_mfma_f32_16x16x32_bf16(a[s], b, acc, 0, 0, 0);
                }
                #pragma unroll
                for (int qq = 0; qq < 4; ++qq) {
                    out[(size_t)(row0 + g * 4 + qq) * D_OUT + t2 * 16 + r] =
                        fmaxf(acc[qq], 0.f);
                }
            }
        }
    }
}

// ================= fallback: proven R11 4-kernel chain =================
__global__ __launch_bounds__(256)
void prep_streams(const float* __restrict__ h, unsigned short* __restrict__ hb,
                  const float* __restrict__ W, unsigned short* __restrict__ wt,
                  int4* __restrict__ cursor4) {
    const int bid = blockIdx.x;
    const int t = threadIdx.x;
    if (bid < NB_CONVH) {
        const size_t idx0 = ((size_t)bid * 256 + t) * 16;
        if (idx0 < (size_t)N_NODES * D_IN) {
            float4 a = *reinterpret_cast<const float4*>(h + idx0);
            float4 b = *reinterpret_cast<const float4*>(h + idx0 + 4);
            float4 c = *reinterpret_cast<const float4*>(h + idx0 + 8);
            float4 d = *reinterpret_cast<const float4*>(h + idx0 + 12);
            uint4 o1, o2;
            o1.x = pack2(a.x, a.y); o1.y = pack2(a.z, a.w);
            o1.z = pack2(b.x, b.y); o1.w = pack2(b.z, b.w);
            o2.x = pack2(c.x, c.y); o2.y = pack2(c.z, c.w);
            o2.z = pack2(d.x, d.y); o2.w = pack2(d.z, d.w);
            *reinterpret_cast<uint4*>(hb + idx0) = o1;
            *reinterpret_cast<uint4*>(hb + idx0 + 8) = o2;
        }
    } else if (bid < NB_CONVH + NB_CONVW) {
        const int tid = (bid - NB_CONVH) * 256 + t;
        const int n = tid >> 4;
        const int k0 = (tid & 15) * 8;
        uint4 o;
        o.x = pack2(W[(size_t)(k0 + 0) * D_OUT + n], W[(size_t)(k0 + 1) * D_OUT + n]);
        o.y = pack2(W[(size_t)(k0 + 2) * D_OUT + n], W[(size_t)(k0 + 3) * D_OUT + n]);
        o.z = pack2(W[(size_t)(k0 + 4) * D_OUT + n], W[(size_t)(k0 + 5) * D_OUT + n]);
        o.w = pack2(W[(size_t)(k0 + 6) * D_OUT + n], W[(size_t)(k0 + 7) * D_OUT + n]);
        *reinterpret_cast<uint4*>(wt + (size_t)n * D_IN + k0) = o;
    } else {
        const int i = (bid - NB_CONVH - NB_CONVW) * 256 + t;
        if (i < N_NODES / 4) cursor4[i] = make_int4(0, 0, 0, 0);
    }
}

__global__ __launch_bounds__(256)
void bucket_fill(const int* __restrict__ esrc, const int* __restrict__ edst,
                 const float* __restrict__ ew, int* __restrict__ cursor,
                 unsigned* __restrict__ bkt) {
    const int e = blockIdx.x * 256 + threadIdx.x;
    if (e >= N_EDGES) return;
    const int d = edst[e];
    const unsigned entry =
        ((unsigned)__half_as_ushort(__float2half(ew[e])) << 16) | (unsigned)esrc[e];
    const int p = atomicAdd(&cursor[d], 1);
    if (p < CAP) bkt[(size_t)d * CAP + p] = entry;
}

__global__ __launch_bounds__(256)
void gather_nodes(const unsigned short* __restrict__ hb,
                  const int* __restrict__ cursor,
                  const unsigned* __restrict__ bkt,
                  unsigned short* __restrict__ xb) {
    const int wv = threadIdx.x >> 6;
    const int lane = threadIdx.x & 63;
    const int n = blockIdx.x * 4 + wv;
    if (n >= N_NODES) return;
    const int cnt = min(cursor[n], CAP);
    const int q  = lane >> 4;
    const int sl = lane & 15;
    float acc0[8] = {0.f, 0.f, 0.f, 0.f, 0.f, 0.f, 0.f, 0.f};
    float acc1[8] = {0.f, 0.f, 0.f, 0.f, 0.f, 0.f, 0.f, 0.f};
    const unsigned ent = bkt[(size_t)n * CAP + lane];
    int j = 0;
    for (; j + 8 <= cnt; j += 8) {
        const unsigned pa = __shfl(ent, j + q, 64);
        const unsigned pb = __shfl(ent, j + 4 + q, 64);
        const uint4 va = *reinterpret_cast<const uint4*>(
            hb + (size_t)(pa & 0xFFFFu) * D_IN + sl * 8);
        const uint4 vb = *reinterpret_cast<const uint4*>(
            hb + (size_t)(pb & 0xFFFFu) * D_IN + sl * 8);
        fma8(va, w16(pa), acc0);
        fma8(vb, w16(pb), acc1);
    }
    for (; j < cnt; j += 4) {
        const int idx = j + q;
        const bool act = idx < cnt;
        const unsigned pr = __shfl(ent, act ? idx : 0, 64);
        const unsigned p = act ? pr : 0u;
        const uint4 v = *reinterpret_cast<const uint4*>(
            hb + (size_t)(p & 0xFFFFu) * D_IN + sl * 8);
        const float w = act ? w16(p) : 0.f;
        fma8(v, w, acc0);
    }
    float s[8];
    #pragma unroll
    for (int k = 0; k < 8; ++k) s[k] = acc0[k] + acc1[k];
    #pragma unroll
    for (int k = 0; k < 8; ++k) s[k] += __shfl_xor(s[k], 16, 64);
    #pragma unroll
    for (int k = 0; k < 8; ++k) s[k] += __shfl_xor(s[k], 32, 64);
    if (q == 0) {
        uint4 o;
        o.x = pack2(s[0], s[1]);
        o.y = pack2(s[2], s[3]);
        o.z = pack2(s[4], s[5]);
        o.w = pack2(s[6], s[7]);
        *reinterpret_cast<uint4*>(xb + (size_t)n * D_IN + sl * 8) = o;
    }
}

__global__ __launch_bounds__(256)
void gemm_mfma(const unsigned short* __restrict__ xb,
               const unsigned short* __restrict__ wt,
               float* __restrict__ out) {
    const int wv = threadIdx.x >> 6;
    const int lane = threadIdx.x & 63;
    const int row0 = blockIdx.x * 64 + wv * 16;
    if (row0 >= N_NODES) return;
    const int g = lane >> 4;
    const int r = lane & 15;
    short8v a[4];
    const unsigned short* arow = xb + (size_t)(row0 + r) * D_IN + g * 8;
    #pragma unroll
    for (int s = 0; s < 4; ++s)
        a[s] = *reinterpret_cast<const short8v*>(arow + 32 * s);
    #pragma unroll
    for (int t = 0; t < 16; ++t) {
        const unsigned short* brow = wt + (size_t)(t * 16 + r) * D_IN + g * 8;
        float4v acc = {0.f, 0.f, 0.f, 0.f};
        #pragma unroll
        for (int s = 0; s < 4; ++s) {
            short8v b = *reinterpret_cast<const short8v*>(brow + 32 * s);
            acc = __builtin_amdgcn_mfma_f32_16x16x32_bf16(a[s], b, acc, 0, 0, 0);
        }
        #pragma unroll
        for (int q = 0; q < 4; ++q) {
            out[(size_t)(row0 + g * 4 + q) * D_OUT + t * 16 + r] = fmaxf(acc[q], 0.f);
        }
    }
}

extern "C" void kernel_launch(void* const* d_in, const int* in_sizes, int n_in,
                              void* d_out, int out_size, void* d_ws, size_t ws_size,
                              hipStream_t stream) {
    const float* h  = (const float*)d_in[0];
    const int* esrc = (const int*)d_in[1];
    const int* edst = (const int*)d_in[2];
    const float* ew = (const float*)d_in[3];
    const float* Wn = (const float*)d_in[4];
    float* out = (float*)d_out;

    // workspace layout (byte offsets)
    char* ws = (char*)d_ws;
    unsigned short* hb  = (unsigned short*)(ws);                // 12,800,000 B
    unsigned short* xb  = (unsigned short*)(ws + 12800000);     // 12,800,000 B
    unsigned short* wt  = (unsigned short*)(ws + 25600000);     //     65,536 B
    int*   cursor       = (int*)(ws + 25665536);                //    200,000 B
    int*   bar          = (int*)(ws + 25865536);                //         32 B
    unsigned* bkt       = (unsigned*)(ws + 25865568);           // 12,800,000 B
    // total 38,665,568 B

    // deterministic co-residency sizing (host-only queries; capture-safe)
    int dev = 0;
    (void)hipGetDevice(&dev);
    int ncu = 0;
    (void)hipDeviceGetAttribute(&ncu, hipDeviceAttributeMultiprocessorCount, dev);
    int maxb = 0;
    hipError_t oe = hipOccupancyMaxActiveBlocksPerMultiprocessor(
        &maxb, (const void*)sage_persist, 256, 0);
    long nblk = (oe == hipSuccess && maxb > 0 && ncu > 0) ? (long)maxb * ncu : 0;
    if (nblk > 8192) nblk = 8192;

    if (nblk >= 512) {
        init_zero<<<(N_NODES / 4 + 255) / 256, 256, 0, stream>>>((int4*)cursor, bar);
        sage_persist<<<dim3((unsigned)nblk), 256, 0, stream>>>(
            h, hb, Wn, wt, cursor, esrc, edst, ew, bkt, xb, out, bar, (int)nblk);
    } else {
        prep_streams<<<NB_CONVH + NB_CONVW + NB_ZERO, 256, 0, stream>>>(
            h, hb, Wn, wt, (int4*)cursor);
        const int eblocks = (N_EDGES + 255) / 256;
        bucket_fill<<<eblocks, 256, 0, stream>>>(esrc, edst, ew, cursor, bkt);
        gather_nodes<<<(N_NODES + 3) / 4, 256, 0, stream>>>(hb, cursor, bkt, xb);
        gemm_mfma<<<(N_NODES + 63) / 64, 256, 0, stream>>>(xb, wt, out);
    }
}

// Round 14
// 300.983 us; speedup vs baseline: 1.4523x; 1.4523x over previous
//
#include <hip/hip_runtime.h>
#include <hip/hip_fp16.h>

#define N_NODES 50000
#define N_EDGES 600000
#define D_IN 128
#define D_OUT 256
#define CAP 64          // bucket capacity per node (Poisson(12): P(deg>=48)~5e-14)

typedef __attribute__((ext_vector_type(8))) short short8v;
typedef __attribute__((ext_vector_type(4))) float float4v;

#define NB_CONVH 1563   // 256 thr * 16 f32 = 4096 elems/block
#define NB_CONVW 16     // 256 thr * 8 elems
#define NB_ZERO  49     // fallback prep: 12500 int4 / 256
#define NUNITS   782    // gemm 64-row units

__device__ inline unsigned bfbits(float f) {
    unsigned u = __float_as_uint(f);
    return (u + 0x7FFFu + ((u >> 16) & 1u)) >> 16;   // RNE f32 -> bf16 bits
}
__device__ inline unsigned pack2(float lo, float hi) {
    return bfbits(lo) | (bfbits(hi) << 16);
}
__device__ inline float w16(unsigned p) {
    return __half2float(__ushort_as_half((unsigned short)(p >> 16)));
}
__device__ inline void fma8(const uint4 v, const float w, float* a) {
    a[0] = fmaf(w, __uint_as_float(v.x << 16), a[0]);
    a[1] = fmaf(w, __uint_as_float(v.x & 0xFFFF0000u), a[1]);
    a[2] = fmaf(w, __uint_as_float(v.y << 16), a[2]);
    a[3] = fmaf(w, __uint_as_float(v.y & 0xFFFF0000u), a[3]);
    a[4] = fmaf(w, __uint_as_float(v.z << 16), a[4]);
    a[5] = fmaf(w, __uint_as_float(v.z & 0xFFFF0000u), a[5]);
    a[6] = fmaf(w, __uint_as_float(v.w << 16), a[6]);
    a[7] = fmaf(w, __uint_as_float(v.w & 0xFFFF0000u), a[7]);
}

// ---- device-scope grid barrier (all blocks co-resident by construction) ----
__device__ inline void grid_barrier(int* bar, int slot, int nblk) {
    __syncthreads();
    if (threadIdx.x == 0) {
        __threadfence();   // release: make this block's writes device-visible
        __hip_atomic_fetch_add(&bar[slot], 1, __ATOMIC_ACQ_REL,
                               __HIP_MEMORY_SCOPE_AGENT);
        long spins = 0;
        while (__hip_atomic_load(&bar[slot], __ATOMIC_ACQUIRE,
                                 __HIP_MEMORY_SCOPE_AGENT) < nblk) {
            __builtin_amdgcn_s_sleep(2);
            if (++spins > (1L << 31)) break;   // safety valve vs infinite hang
        }
    }
    __syncthreads();
}

// ---------- init: zero cursor + barrier slots ----------
__global__ __launch_bounds__(256)
void init_zero(int4* __restrict__ cursor4, int* __restrict__ bar) {
    const int i = blockIdx.x * 256 + threadIdx.x;
    if (i < N_NODES / 4) cursor4[i] = make_int4(0, 0, 0, 0);
    if (blockIdx.x == 0 && threadIdx.x < 8) bar[threadIdx.x] = 0;
}

// ---------- persistent fused kernel: {bucket|convH|convW} -> gather -> gemm --
// launch_bounds(256,4): 128-VGPR budget -> NO spill (R13's (256,8)=32 VGPR
// forced 170MB of scratch traffic, 740us).
__global__ __launch_bounds__(256, 4)
void sage_persist(const float* __restrict__ h, unsigned short* __restrict__ hb,
                  const float* __restrict__ W, unsigned short* __restrict__ wt,
                  int* __restrict__ cursor,
                  const int* __restrict__ esrc, const int* __restrict__ edst,
                  const float* __restrict__ ew, unsigned* __restrict__ bkt,
                  unsigned short* __restrict__ xb, float* __restrict__ out,
                  int* __restrict__ bar, int nblk) {
    const int t = threadIdx.x;
    const int wv = t >> 6;
    const int lane = t & 63;
    const int bid0 = blockIdx.x;

    // ---- Phase A: bucket fill (grid-stride edges; cursor zeroed by init) ----
    for (int e = bid0 * 256 + t; e < N_EDGES; e += nblk * 256) {
        const int d = edst[e];
        const unsigned entry =
            ((unsigned)__half_as_ushort(__float2half(ew[e])) << 16) | (unsigned)esrc[e];
        const int p = atomicAdd(&cursor[d], 1);
        if (p < CAP) bkt[(size_t)d * CAP + p] = entry;
    }
    // ---- Phase B: h -> bf16 (independent of A; overlaps other blocks' A) ----
    for (int b = bid0; b < NB_CONVH; b += nblk) {
        const size_t idx0 = ((size_t)b * 256 + t) * 16;
        if (idx0 < (size_t)N_NODES * D_IN) {
            float4 a = *reinterpret_cast<const float4*>(h + idx0);
            float4 bb = *reinterpret_cast<const float4*>(h + idx0 + 4);
            float4 c = *reinterpret_cast<const float4*>(h + idx0 + 8);
            float4 d = *reinterpret_cast<const float4*>(h + idx0 + 12);
            uint4 o1, o2;
            o1.x = pack2(a.x, a.y);  o1.y = pack2(a.z, a.w);
            o1.z = pack2(bb.x, bb.y); o1.w = pack2(bb.z, bb.w);
            o2.x = pack2(c.x, c.y);  o2.y = pack2(c.z, c.w);
            o2.z = pack2(d.x, d.y);  o2.w = pack2(d.z, d.w);
            *reinterpret_cast<uint4*>(hb + idx0) = o1;
            *reinterpret_cast<uint4*>(hb + idx0 + 8) = o2;
        }
    }
    // ---- Phase C: W -> Wt bf16 ----
    for (int b = bid0; b < NB_CONVW; b += nblk) {
        const int tid = b * 256 + t;
        const int n = tid >> 4;
        const int k0 = (tid & 15) * 8;
        uint4 o;
        o.x = pack2(W[(size_t)(k0 + 0) * D_OUT + n], W[(size_t)(k0 + 1) * D_OUT + n]);
        o.y = pack2(W[(size_t)(k0 + 2) * D_OUT + n], W[(size_t)(k0 + 3) * D_OUT + n]);
        o.z = pack2(W[(size_t)(k0 + 4) * D_OUT + n], W[(size_t)(k0 + 5) * D_OUT + n]);
        o.w = pack2(W[(size_t)(k0 + 6) * D_OUT + n], W[(size_t)(k0 + 7) * D_OUT + n]);
        *reinterpret_cast<uint4*>(wt + (size_t)n * D_IN + k0) = o;
    }

    grid_barrier(bar, 0, nblk);

    // ---- Phase D: gather-reduce, 1 node/wave (grid-stride waves) ----
    {
        const int q  = lane >> 4;
        const int sl = lane & 15;
        for (int n = bid0 * 4 + wv; n < N_NODES; n += nblk * 4) {
            const int cnt = min(cursor[n], CAP);
            float acc0[8] = {0.f, 0.f, 0.f, 0.f, 0.f, 0.f, 0.f, 0.f};
            float acc1[8] = {0.f, 0.f, 0.f, 0.f, 0.f, 0.f, 0.f, 0.f};
            const unsigned ent = bkt[(size_t)n * CAP + lane];   // 256B wave load
            int j = 0;
            for (; j + 8 <= cnt; j += 8) {
                const unsigned pa = __shfl(ent, j + q, 64);
                const unsigned pb = __shfl(ent, j + 4 + q, 64);
                const uint4 va = *reinterpret_cast<const uint4*>(
                    hb + (size_t)(pa & 0xFFFFu) * D_IN + sl * 8);
                const uint4 vb = *reinterpret_cast<const uint4*>(
                    hb + (size_t)(pb & 0xFFFFu) * D_IN + sl * 8);
                fma8(va, w16(pa), acc0);
                fma8(vb, w16(pb), acc1);
            }
            for (; j < cnt; j += 4) {
                const int idx = j + q;
                const bool act = idx < cnt;
                const unsigned pr = __shfl(ent, act ? idx : 0, 64);
                const unsigned p = act ? pr : 0u;
                const uint4 v = *reinterpret_cast<const uint4*>(
                    hb + (size_t)(p & 0xFFFFu) * D_IN + sl * 8);
                const float w = act ? w16(p) : 0.f;
                fma8(v, w, acc0);
            }
            float s[8];
            #pragma unroll
            for (int k = 0; k < 8; ++k) s[k] = acc0[k] + acc1[k];
            #pragma unroll
            for (int k = 0; k < 8; ++k) s[k] += __shfl_xor(s[k], 16, 64);
            #pragma unroll
            for (int k = 0; k < 8; ++k) s[k] += __shfl_xor(s[k], 32, 64);
            if (q == 0) {
                uint4 o;
                o.x = pack2(s[0], s[1]);
                o.y = pack2(s[2], s[3]);
                o.z = pack2(s[4], s[5]);
                o.w = pack2(s[6], s[7]);
                *reinterpret_cast<uint4*>(xb + (size_t)n * D_IN + sl * 8) = o;
            }
        }
    }

    grid_barrier(bar, 1, nblk);

    // ---- Phase E: gemm out = relu(xb @ wt^T) (grid-stride 64-row units) ----
    {
        const int g = lane >> 4;
        const int r = lane & 15;
        for (int u = bid0; u < NUNITS; u += nblk) {
            const int row0 = u * 64 + wv * 16;
            if (row0 >= N_NODES) continue;
            short8v a[4];
            const unsigned short* arow = xb + (size_t)(row0 + r) * D_IN + g * 8;
            #pragma unroll
            for (int s = 0; s < 4; ++s)
                a[s] = *reinterpret_cast<const short8v*>(arow + 32 * s);
            #pragma unroll
            for (int t2 = 0; t2 < 16; ++t2) {
                const unsigned short* brow = wt + (size_t)(t2 * 16 + r) * D_IN + g * 8;
                float4v acc = {0.f, 0.f, 0.f, 0.f};
                #pragma unroll
                for (int s = 0; s < 4; ++s) {
                    short8v b = *reinterpret_cast<const short8v*>(brow + 32 * s);
                    acc = __builtin_amdgcn_mfma_f32_16x16x32_bf16(a[s], b, acc, 0, 0, 0);
                }
                #pragma unroll
                for (int qq = 0; qq < 4; ++qq) {
                    out[(size_t)(row0 + g * 4 + qq) * D_OUT + t2 * 16 + r] =
                        fmaxf(acc[qq], 0.f);
                }
            }
        }
    }
}

// ================= fallback: proven R11 4-kernel chain =================
__global__ __launch_bounds__(256)
void prep_streams(const float* __restrict__ h, unsigned short* __restrict__ hb,
                  const float* __restrict__ W, unsigned short* __restrict__ wt,
                  int4* __restrict__ cursor4) {
    const int bid = blockIdx.x;
    const int t = threadIdx.x;
    if (bid < NB_CONVH) {
        const size_t idx0 = ((size_t)bid * 256 + t) * 16;
        if (idx0 < (size_t)N_NODES * D_IN) {
            float4 a = *reinterpret_cast<const float4*>(h + idx0);
            float4 b = *reinterpret_cast<const float4*>(h + idx0 + 4);
            float4 c = *reinterpret_cast<const float4*>(h + idx0 + 8);
            float4 d = *reinterpret_cast<const float4*>(h + idx0 + 12);
            uint4 o1, o2;
            o1.x = pack2(a.x, a.y); o1.y = pack2(a.z, a.w);
            o1.z = pack2(b.x, b.y); o1.w = pack2(b.z, b.w);
            o2.x = pack2(c.x, c.y); o2.y = pack2(c.z, c.w);
            o2.z = pack2(d.x, d.y); o2.w = pack2(d.z, d.w);
            *reinterpret_cast<uint4*>(hb + idx0) = o1;
            *reinterpret_cast<uint4*>(hb + idx0 + 8) = o2;
        }
    } else if (bid < NB_CONVH + NB_CONVW) {
        const int tid = (bid - NB_CONVH) * 256 + t;
        const int n = tid >> 4;
        const int k0 = (tid & 15) * 8;
        uint4 o;
        o.x = pack2(W[(size_t)(k0 + 0) * D_OUT + n], W[(size_t)(k0 + 1) * D_OUT + n]);
        o.y = pack2(W[(size_t)(k0 + 2) * D_OUT + n], W[(size_t)(k0 + 3) * D_OUT + n]);
        o.z = pack2(W[(size_t)(k0 + 4) * D_OUT + n], W[(size_t)(k0 + 5) * D_OUT + n]);
        o.w = pack2(W[(size_t)(k0 + 6) * D_OUT + n], W[(size_t)(k0 + 7) * D_OUT + n]);
        *reinterpret_cast<uint4*>(wt + (size_t)n * D_IN + k0) = o;
    } else {
        const int i = (bid - NB_CONVH - NB_CONVW) * 256 + t;
        if (i < N_NODES / 4) cursor4[i] = make_int4(0, 0, 0, 0);
    }
}

__global__ __launch_bounds__(256)
void bucket_fill(const int* __restrict__ esrc, const int* __restrict__ edst,
                 const float* __restrict__ ew, int* __restrict__ cursor,
                 unsigned* __restrict__ bkt) {
    const int e = blockIdx.x * 256 + threadIdx.x;
    if (e >= N_EDGES) return;
    const int d = edst[e];
    const unsigned entry =
        ((unsigned)__half_as_ushort(__float2half(ew[e])) << 16) | (unsigned)esrc[e];
    const int p = atomicAdd(&cursor[d], 1);
    if (p < CAP) bkt[(size_t)d * CAP + p] = entry;
}

__global__ __launch_bounds__(256)
void gather_nodes(const unsigned short* __restrict__ hb,
                  const int* __restrict__ cursor,
                  const unsigned* __restrict__ bkt,
                  unsigned short* __restrict__ xb) {
    const int wv = threadIdx.x >> 6;
    const int lane = threadIdx.x & 63;
    const int n = blockIdx.x * 4 + wv;
    if (n >= N_NODES) return;
    const int cnt = min(cursor[n], CAP);
    const int q  = lane >> 4;
    const int sl = lane & 15;
    float acc0[8] = {0.f, 0.f, 0.f, 0.f, 0.f, 0.f, 0.f, 0.f};
    float acc1[8] = {0.f, 0.f, 0.f, 0.f, 0.f, 0.f, 0.f, 0.f};
    const unsigned ent = bkt[(size_t)n * CAP + lane];
    int j = 0;
    for (; j + 8 <= cnt; j += 8) {
        const unsigned pa = __shfl(ent, j + q, 64);
        const unsigned pb = __shfl(ent, j + 4 + q, 64);
        const uint4 va = *reinterpret_cast<const uint4*>(
            hb + (size_t)(pa & 0xFFFFu) * D_IN + sl * 8);
        const uint4 vb = *reinterpret_cast<const uint4*>(
            hb + (size_t)(pb & 0xFFFFu) * D_IN + sl * 8);
        fma8(va, w16(pa), acc0);
        fma8(vb, w16(pb), acc1);
    }
    for (; j < cnt; j += 4) {
        const int idx = j + q;
        const bool act = idx < cnt;
        const unsigned pr = __shfl(ent, act ? idx : 0, 64);
        const unsigned p = act ? pr : 0u;
        const uint4 v = *reinterpret_cast<const uint4*>(
            hb + (size_t)(p & 0xFFFFu) * D_IN + sl * 8);
        const float w = act ? w16(p) : 0.f;
        fma8(v, w, acc0);
    }
    float s[8];
    #pragma unroll
    for (int k = 0; k < 8; ++k) s[k] = acc0[k] + acc1[k];
    #pragma unroll
    for (int k = 0; k < 8; ++k) s[k] += __shfl_xor(s[k], 16, 64);
    #pragma unroll
    for (int k = 0; k < 8; ++k) s[k] += __shfl_xor(s[k], 32, 64);
    if (q == 0) {
        uint4 o;
        o.x = pack2(s[0], s[1]);
        o.y = pack2(s[2], s[3]);
        o.z = pack2(s[4], s[5]);
        o.w = pack2(s[6], s[7]);
        *reinterpret_cast<uint4*>(xb + (size_t)n * D_IN + sl * 8) = o;
    }
}

__global__ __launch_bounds__(256)
void gemm_mfma(const unsigned short* __restrict__ xb,
               const unsigned short* __restrict__ wt,
               float* __restrict__ out) {
    const int wv = threadIdx.x >> 6;
    const int lane = threadIdx.x & 63;
    const int row0 = blockIdx.x * 64 + wv * 16;
    if (row0 >= N_NODES) return;
    const int g = lane >> 4;
    const int r = lane & 15;
    short8v a[4];
    const unsigned short* arow = xb + (size_t)(row0 + r) * D_IN + g * 8;
    #pragma unroll
    for (int s = 0; s < 4; ++s)
        a[s] = *reinterpret_cast<const short8v*>(arow + 32 * s);
    #pragma unroll
    for (int t = 0; t < 16; ++t) {
        const unsigned short* brow = wt + (size_t)(t * 16 + r) * D_IN + g * 8;
        float4v acc = {0.f, 0.f, 0.f, 0.f};
        #pragma unroll
        for (int s = 0; s < 4; ++s) {
            short8v b = *reinterpret_cast<const short8v*>(brow + 32 * s);
            acc = __builtin_amdgcn_mfma_f32_16x16x32_bf16(a[s], b, acc, 0, 0, 0);
        }
        #pragma unroll
        for (int q = 0; q < 4; ++q) {
            out[(size_t)(row0 + g * 4 + q) * D_OUT + t * 16 + r] = fmaxf(acc[q], 0.f);
        }
    }
}

extern "C" void kernel_launch(void* const* d_in, const int* in_sizes, int n_in,
                              void* d_out, int out_size, void* d_ws, size_t ws_size,
                              hipStream_t stream) {
    const float* h  = (const float*)d_in[0];
    const int* esrc = (const int*)d_in[1];
    const int* edst = (const int*)d_in[2];
    const float* ew = (const float*)d_in[3];
    const float* Wn = (const float*)d_in[4];
    float* out = (float*)d_out;

    // workspace layout (byte offsets)
    char* ws = (char*)d_ws;
    unsigned short* hb  = (unsigned short*)(ws);                // 12,800,000 B
    unsigned short* xb  = (unsigned short*)(ws + 12800000);     // 12,800,000 B
    unsigned short* wt  = (unsigned short*)(ws + 25600000);     //     65,536 B
    int*   cursor       = (int*)(ws + 25665536);                //    200,000 B
    int*   bar          = (int*)(ws + 25865536);                //         32 B
    unsigned* bkt       = (unsigned*)(ws + 25865568);           // 12,800,000 B
    // total 38,665,568 B

    // deterministic co-residency sizing (host-only queries; capture-safe)
    int dev = 0;
    (void)hipGetDevice(&dev);
    int ncu = 0;
    (void)hipDeviceGetAttribute(&ncu, hipDeviceAttributeMultiprocessorCount, dev);
    int maxb = 0;
    hipError_t oe = hipOccupancyMaxActiveBlocksPerMultiprocessor(
        &maxb, (const void*)sage_persist, 256, 0);
    long nblk = (oe == hipSuccess && maxb > 0 && ncu > 0) ? (long)maxb * ncu : 0;
    if (nblk > 8192) nblk = 8192;

    if (nblk >= 512) {
        init_zero<<<(N_NODES / 4 + 255) / 256, 256, 0, stream>>>((int4*)cursor, bar);
        sage_persist<<<dim3((unsigned)nblk), 256, 0, stream>>>(
            h, hb, Wn, wt, cursor, esrc, edst, ew, bkt, xb, out, bar, (int)nblk);
    } else {
        prep_streams<<<NB_CONVH + NB_CONVW + NB_ZERO, 256, 0, stream>>>(
            h, hb, Wn, wt, (int4*)cursor);
        const int eblocks = (N_EDGES + 255) / 256;
        bucket_fill<<<eblocks, 256, 0, stream>>>(esrc, edst, ew, cursor, bkt);
        gather_nodes<<<(N_NODES + 3) / 4, 256, 0, stream>>>(hb, cursor, bkt, xb);
        gemm_mfma<<<(N_NODES + 63) / 64, 256, 0, stream>>>(xb, wt, out);
    }
}

// Round 15
// 104.822 us; speedup vs baseline: 4.1702x; 2.8714x over previous
//
#include <hip/hip_runtime.h>
#include <hip/hip_fp16.h>

#define N_NODES 50000
#define N_EDGES 600000
#define D_IN 128
#define D_OUT 256
#define CAP 64          // bucket capacity per node (Poisson(12): P(deg>=48)~5e-14)

typedef __attribute__((ext_vector_type(8))) short short8v;
typedef __attribute__((ext_vector_type(4))) float float4v;

#define NB_EDGE  2344   // 1 edge/thread bucket blocks (FIRST: atomics overlap stream)
#define NB_CONVH 1563   // 256 thr * 16 f32 = 4096 elems/block
#define NB_CONVW 16     // 256 thr * 8 elems

__device__ inline unsigned bfbits(float f) {
    unsigned u = __float_as_uint(f);
    return (u + 0x7FFFu + ((u >> 16) & 1u)) >> 16;   // RNE f32 -> bf16 bits
}
__device__ inline unsigned pack2(float lo, float hi) {
    return bfbits(lo) | (bfbits(hi) << 16);
}
__device__ inline float w16(unsigned p) {
    return __half2float(__ushort_as_half((unsigned short)(p >> 16)));
}
__device__ inline void fma8(const uint4 v, const float w, float* a) {
    a[0] = fmaf(w, __uint_as_float(v.x << 16), a[0]);
    a[1] = fmaf(w, __uint_as_float(v.x & 0xFFFF0000u), a[1]);
    a[2] = fmaf(w, __uint_as_float(v.y << 16), a[2]);
    a[3] = fmaf(w, __uint_as_float(v.y & 0xFFFF0000u), a[3]);
    a[4] = fmaf(w, __uint_as_float(v.z << 16), a[4]);
    a[5] = fmaf(w, __uint_as_float(v.z & 0xFFFF0000u), a[5]);
    a[6] = fmaf(w, __uint_as_float(v.w << 16), a[6]);
    a[7] = fmaf(w, __uint_as_float(v.w & 0xFFFF0000u), a[7]);
}

// ---------- K1: zero cursor (own kernel; rocclr fill path measured 41us) ----
__global__ __launch_bounds__(256)
void zero_cursor(int4* __restrict__ cursor4) {
    const int i = blockIdx.x * 256 + threadIdx.x;
    if (i < N_NODES / 4) cursor4[i] = make_int4(0, 0, 0, 0);
}

// ---------- K2: bucket fill (blocks first) ∥ h->bf16 ∥ W->Wt bf16 ----------
__global__ __launch_bounds__(256)
void prep_bucket(const int* __restrict__ esrc, const int* __restrict__ edst,
                 const float* __restrict__ ew, int* __restrict__ cursor,
                 unsigned* __restrict__ bkt,
                 const float* __restrict__ h, unsigned short* __restrict__ hb,
                 const float* __restrict__ W, unsigned short* __restrict__ wt) {
    const int bid = blockIdx.x;
    const int t = threadIdx.x;
    if (bid < NB_EDGE) {
        const int e = bid * 256 + t;
        if (e < N_EDGES) {
            const int d = edst[e];
            const unsigned entry =
                ((unsigned)__half_as_ushort(__float2half(ew[e])) << 16) | (unsigned)esrc[e];
            const int p = atomicAdd(&cursor[d], 1);
            if (p < CAP) bkt[(size_t)d * CAP + p] = entry;
        }
    } else if (bid < NB_EDGE + NB_CONVH) {
        const size_t idx0 = ((size_t)(bid - NB_EDGE) * 256 + t) * 16;
        if (idx0 < (size_t)N_NODES * D_IN) {   // multiple of 16 -> full/none
            float4 a = *reinterpret_cast<const float4*>(h + idx0);
            float4 b = *reinterpret_cast<const float4*>(h + idx0 + 4);
            float4 c = *reinterpret_cast<const float4*>(h + idx0 + 8);
            float4 d = *reinterpret_cast<const float4*>(h + idx0 + 12);
            uint4 o1, o2;
            o1.x = pack2(a.x, a.y); o1.y = pack2(a.z, a.w);
            o1.z = pack2(b.x, b.y); o1.w = pack2(b.z, b.w);
            o2.x = pack2(c.x, c.y); o2.y = pack2(c.z, c.w);
            o2.z = pack2(d.x, d.y); o2.w = pack2(d.z, d.w);
            *reinterpret_cast<uint4*>(hb + idx0) = o1;
            *reinterpret_cast<uint4*>(hb + idx0 + 8) = o2;
        }
    } else {
        const int tid = (bid - NB_EDGE - NB_CONVH) * 256 + t;
        const int n = tid >> 4;
        const int k0 = (tid & 15) * 8;
        uint4 o;
        o.x = pack2(W[(size_t)(k0 + 0) * D_OUT + n], W[(size_t)(k0 + 1) * D_OUT + n]);
        o.y = pack2(W[(size_t)(k0 + 2) * D_OUT + n], W[(size_t)(k0 + 3) * D_OUT + n]);
        o.z = pack2(W[(size_t)(k0 + 4) * D_OUT + n], W[(size_t)(k0 + 5) * D_OUT + n]);
        o.w = pack2(W[(size_t)(k0 + 6) * D_OUT + n], W[(size_t)(k0 + 7) * D_OUT + n]);
        *reinterpret_cast<uint4*>(wt + (size_t)n * D_IN + k0) = o;
    }
}

// ---------- K3: gather-reduce, 1 node/wave, 16B/lane, 4 edges/instr --------
__global__ __launch_bounds__(256)
void gather_nodes(const unsigned short* __restrict__ hb,
                  const int* __restrict__ cursor,
                  const unsigned* __restrict__ bkt,
                  unsigned short* __restrict__ xb) {
    const int wv = threadIdx.x >> 6;
    const int lane = threadIdx.x & 63;
    const int n = blockIdx.x * 4 + wv;
    if (n >= N_NODES) return;
    const int cnt = min(cursor[n], CAP);
    const int q  = lane >> 4;          // edge slot within quad
    const int sl = lane & 15;          // dims sl*8 .. sl*8+7
    float acc0[8] = {0.f, 0.f, 0.f, 0.f, 0.f, 0.f, 0.f, 0.f};
    float acc1[8] = {0.f, 0.f, 0.f, 0.f, 0.f, 0.f, 0.f, 0.f};

    const unsigned ent = bkt[(size_t)n * CAP + lane];   // 256B aligned wave load
    int j = 0;
    for (; j + 8 <= cnt; j += 8) {
        const unsigned pa = __shfl(ent, j + q, 64);
        const unsigned pb = __shfl(ent, j + 4 + q, 64);
        const uint4 va = *reinterpret_cast<const uint4*>(
            hb + (size_t)(pa & 0xFFFFu) * D_IN + sl * 8);
        const uint4 vb = *reinterpret_cast<const uint4*>(
            hb + (size_t)(pb & 0xFFFFu) * D_IN + sl * 8);
        fma8(va, w16(pa), acc0);
        fma8(vb, w16(pb), acc1);
    }
    for (; j < cnt; j += 4) {
        const int idx = j + q;
        const bool act = idx < cnt;
        const unsigned pr = __shfl(ent, act ? idx : 0, 64);
        const unsigned p = act ? pr : 0u;
        const uint4 v = *reinterpret_cast<const uint4*>(
            hb + (size_t)(p & 0xFFFFu) * D_IN + sl * 8);
        const float w = act ? w16(p) : 0.f;
        fma8(v, w, acc0);
    }
    float s[8];
    #pragma unroll
    for (int k = 0; k < 8; ++k) s[k] = acc0[k] + acc1[k];
    #pragma unroll
    for (int k = 0; k < 8; ++k) s[k] += __shfl_xor(s[k], 16, 64);
    #pragma unroll
    for (int k = 0; k < 8; ++k) s[k] += __shfl_xor(s[k], 32, 64);
    if (q == 0) {
        uint4 o;
        o.x = pack2(s[0], s[1]);
        o.y = pack2(s[2], s[3]);
        o.z = pack2(s[4], s[5]);
        o.w = pack2(s[6], s[7]);
        *reinterpret_cast<uint4*>(xb + (size_t)n * D_IN + sl * 8) = o;
    }
}

// ---------- K4: out = relu(x_bf16 @ Wt^T) via MFMA ----------
__global__ __launch_bounds__(256)
void gemm_mfma(const unsigned short* __restrict__ xb,
               const unsigned short* __restrict__ wt,
               float* __restrict__ out) {
    const int wv = threadIdx.x >> 6;
    const int lane = threadIdx.x & 63;
    const int row0 = blockIdx.x * 64 + wv * 16;
    if (row0 >= N_NODES) return;
    const int g = lane >> 4;
    const int r = lane & 15;

    short8v a[4];
    const unsigned short* arow = xb + (size_t)(row0 + r) * D_IN + g * 8;
    #pragma unroll
    for (int s = 0; s < 4; ++s)
        a[s] = *reinterpret_cast<const short8v*>(arow + 32 * s);

    #pragma unroll
    for (int t = 0; t < 16; ++t) {
        const unsigned short* brow = wt + (size_t)(t * 16 + r) * D_IN + g * 8;
        float4v acc = {0.f, 0.f, 0.f, 0.f};
        #pragma unroll
        for (int s = 0; s < 4; ++s) {
            short8v b = *reinterpret_cast<const short8v*>(brow + 32 * s);
            acc = __builtin_amdgcn_mfma_f32_16x16x32_bf16(a[s], b, acc, 0, 0, 0);
        }
        #pragma unroll
        for (int q = 0; q < 4; ++q) {
            out[(size_t)(row0 + g * 4 + q) * D_OUT + t * 16 + r] = fmaxf(acc[q], 0.f);
        }
    }
}

extern "C" void kernel_launch(void* const* d_in, const int* in_sizes, int n_in,
                              void* d_out, int out_size, void* d_ws, size_t ws_size,
                              hipStream_t stream) {
    const float* h  = (const float*)d_in[0];
    const int* esrc = (const int*)d_in[1];
    const int* edst = (const int*)d_in[2];
    const float* ew = (const float*)d_in[3];
    const float* Wn = (const float*)d_in[4];
    float* out = (float*)d_out;

    // workspace layout (byte offsets)
    char* ws = (char*)d_ws;
    unsigned short* hb  = (unsigned short*)(ws);                // 12,800,000 B
    unsigned short* xb  = (unsigned short*)(ws + 12800000);     // 12,800,000 B
    unsigned short* wt  = (unsigned short*)(ws + 25600000);     //     65,536 B
    int*   cursor       = (int*)(ws + 25665536);                //    200,000 B
    unsigned* bkt       = (unsigned*)(ws + 25865536);           // 12,800,000 B
    // total 38,665,536 B

    zero_cursor<<<(N_NODES / 4 + 255) / 256, 256, 0, stream>>>((int4*)cursor);
    prep_bucket<<<NB_EDGE + NB_CONVH + NB_CONVW, 256, 0, stream>>>(
        esrc, edst, ew, cursor, bkt, h, hb, Wn, wt);
    gather_nodes<<<(N_NODES + 3) / 4, 256, 0, stream>>>(hb, cursor, bkt, xb);
    gemm_mfma<<<(N_NODES + 63) / 64, 256, 0, stream>>>(xb, wt, out);
}

// Round 16
// 100.077 us; speedup vs baseline: 4.3679x; 1.0474x over previous
//
#include <hip/hip_runtime.h>
#include <hip/hip_fp16.h>

#define N_NODES 50000
#define N_EDGES 600000
#define D_IN 128
#define D_OUT 256
#define CAP 64          // bucket capacity per node (Poisson(12): P(deg>=48)~5e-14)

typedef __attribute__((ext_vector_type(8))) short short8v;
typedef __attribute__((ext_vector_type(4))) float float4v;

#define NB_CONVH 1563   // 256 thr * 16 f32 = 4096 elems/block
#define NB_CONVW 16     // 256 thr * 8 elems
#define NB_ZERO  49     // 12500 int4 / 256

__device__ inline unsigned bfbits(float f) {
    unsigned u = __float_as_uint(f);
    return (u + 0x7FFFu + ((u >> 16) & 1u)) >> 16;   // RNE f32 -> bf16 bits
}
__device__ inline unsigned pack2(float lo, float hi) {
    return bfbits(lo) | (bfbits(hi) << 16);
}
__device__ inline float w16(unsigned p) {
    return __half2float(__ushort_as_half((unsigned short)(p >> 16)));
}
// 8 bf16 lanes of a uint4 -> fma into acc[8] (static indices -> registers)
__device__ inline void fma8(const uint4 v, const float w, float* a) {
    a[0] = fmaf(w, __uint_as_float(v.x << 16), a[0]);
    a[1] = fmaf(w, __uint_as_float(v.x & 0xFFFF0000u), a[1]);
    a[2] = fmaf(w, __uint_as_float(v.y << 16), a[2]);
    a[3] = fmaf(w, __uint_as_float(v.y & 0xFFFF0000u), a[3]);
    a[4] = fmaf(w, __uint_as_float(v.z << 16), a[4]);
    a[5] = fmaf(w, __uint_as_float(v.z & 0xFFFF0000u), a[5]);
    a[6] = fmaf(w, __uint_as_float(v.w << 16), a[6]);
    a[7] = fmaf(w, __uint_as_float(v.w & 0xFFFF0000u), a[7]);
}

// ---------- Stage 0: streaming prep: h->bf16, W->Wt bf16, zero cursor ------
__global__ __launch_bounds__(256)
void prep_streams(const float* __restrict__ h, unsigned short* __restrict__ hb,
                  const float* __restrict__ W, unsigned short* __restrict__ wt,
                  int4* __restrict__ cursor4) {
    const int bid = blockIdx.x;
    const int t = threadIdx.x;
    if (bid < NB_CONVH) {
        const size_t idx0 = ((size_t)bid * 256 + t) * 16;
        if (idx0 < (size_t)N_NODES * D_IN) {   // multiple of 16 -> full/none
            float4 a = *reinterpret_cast<const float4*>(h + idx0);
            float4 b = *reinterpret_cast<const float4*>(h + idx0 + 4);
            float4 c = *reinterpret_cast<const float4*>(h + idx0 + 8);
            float4 d = *reinterpret_cast<const float4*>(h + idx0 + 12);
            uint4 o1, o2;
            o1.x = pack2(a.x, a.y); o1.y = pack2(a.z, a.w);
            o1.z = pack2(b.x, b.y); o1.w = pack2(b.z, b.w);
            o2.x = pack2(c.x, c.y); o2.y = pack2(c.z, c.w);
            o2.z = pack2(d.x, d.y); o2.w = pack2(d.z, d.w);
            *reinterpret_cast<uint4*>(hb + idx0) = o1;
            *reinterpret_cast<uint4*>(hb + idx0 + 8) = o2;
        }
    } else if (bid < NB_CONVH + NB_CONVW) {
        const int tid = (bid - NB_CONVH) * 256 + t;
        const int n = tid >> 4;
        const int k0 = (tid & 15) * 8;
        uint4 o;
        o.x = pack2(W[(size_t)(k0 + 0) * D_OUT + n], W[(size_t)(k0 + 1) * D_OUT + n]);
        o.y = pack2(W[(size_t)(k0 + 2) * D_OUT + n], W[(size_t)(k0 + 3) * D_OUT + n]);
        o.z = pack2(W[(size_t)(k0 + 4) * D_OUT + n], W[(size_t)(k0 + 5) * D_OUT + n]);
        o.w = pack2(W[(size_t)(k0 + 6) * D_OUT + n], W[(size_t)(k0 + 7) * D_OUT + n]);
        *reinterpret_cast<uint4*>(wt + (size_t)n * D_IN + k0) = o;
    } else {
        const int i = (bid - NB_CONVH - NB_CONVW) * 256 + t;
        if (i < N_NODES / 4) cursor4[i] = make_int4(0, 0, 0, 0);
    }
}

// ---------- Stage 1: bucket fill — replaces hist+scan+fill ----------
// entry = (fp16(weight) << 16) | src   (src < 50000 < 2^16)
__global__ __launch_bounds__(256)
void bucket_fill(const int* __restrict__ esrc, const int* __restrict__ edst,
                 const float* __restrict__ ew, int* __restrict__ cursor,
                 unsigned* __restrict__ bkt) {
    const int e = blockIdx.x * 256 + threadIdx.x;
    if (e >= N_EDGES) return;
    const int d = edst[e];
    const unsigned entry =
        ((unsigned)__half_as_ushort(__float2half(ew[e])) << 16) | (unsigned)esrc[e];
    const int p = atomicAdd(&cursor[d], 1);
    if (p < CAP) bkt[(size_t)d * CAP + p] = entry;
}

// ---------- Stage 2: gather-reduce, 1 node/wave, 16B/lane, 4 edges/instr ---
// Bucket is one aligned 256B wave-load; entries >= cnt are poison and masked.
__global__ __launch_bounds__(256)
void gather_nodes(const unsigned short* __restrict__ hb,
                  const int* __restrict__ cursor,
                  const unsigned* __restrict__ bkt,
                  unsigned short* __restrict__ xb) {
    const int wv = threadIdx.x >> 6;
    const int lane = threadIdx.x & 63;
    const int n = blockIdx.x * 4 + wv;
    if (n >= N_NODES) return;
    const int cnt = min(cursor[n], CAP);
    const int q  = lane >> 4;          // edge slot within quad
    const int sl = lane & 15;          // dims sl*8 .. sl*8+7
    float acc0[8] = {0.f, 0.f, 0.f, 0.f, 0.f, 0.f, 0.f, 0.f};
    float acc1[8] = {0.f, 0.f, 0.f, 0.f, 0.f, 0.f, 0.f, 0.f};

    const unsigned ent = bkt[(size_t)n * CAP + lane];   // 256B aligned wave load
    int j = 0;
    for (; j + 8 <= cnt; j += 8) {
        const unsigned pa = __shfl(ent, j + q, 64);
        const unsigned pb = __shfl(ent, j + 4 + q, 64);
        const uint4 va = *reinterpret_cast<const uint4*>(
            hb + (size_t)(pa & 0xFFFFu) * D_IN + sl * 8);
        const uint4 vb = *reinterpret_cast<const uint4*>(
            hb + (size_t)(pb & 0xFFFFu) * D_IN + sl * 8);
        fma8(va, w16(pa), acc0);
        fma8(vb, w16(pb), acc1);
    }
    for (; j < cnt; j += 4) {
        const int idx = j + q;
        const bool act = idx < cnt;
        const unsigned pr = __shfl(ent, act ? idx : 0, 64);
        const unsigned p = act ? pr : 0u;          // lane-0 row: always valid
        const uint4 v = *reinterpret_cast<const uint4*>(
            hb + (size_t)(p & 0xFFFFu) * D_IN + sl * 8);
        const float w = act ? w16(p) : 0.f;
        fma8(v, w, acc0);
    }
    float s[8];
    #pragma unroll
    for (int k = 0; k < 8; ++k) s[k] = acc0[k] + acc1[k];
    #pragma unroll
    for (int k = 0; k < 8; ++k) s[k] += __shfl_xor(s[k], 16, 64);
    #pragma unroll
    for (int k = 0; k < 8; ++k) s[k] += __shfl_xor(s[k], 32, 64);
    if (q == 0) {
        uint4 o;
        o.x = pack2(s[0], s[1]);
        o.y = pack2(s[2], s[3]);
        o.z = pack2(s[4], s[5]);
        o.w = pack2(s[6], s[7]);
        *reinterpret_cast<uint4*>(xb + (size_t)n * D_IN + sl * 8) = o;
    }
}

// ---------- Stage 3: out = relu(x_bf16 @ Wt^T) via MFMA ----------
// out stores are nontemporal: 51.2 MB streamed once, never re-read.
__global__ __launch_bounds__(256)
void gemm_mfma(const unsigned short* __restrict__ xb,
               const unsigned short* __restrict__ wt,
               float* __restrict__ out) {
    const int wv = threadIdx.x >> 6;
    const int lane = threadIdx.x & 63;
    const int row0 = blockIdx.x * 64 + wv * 16;
    if (row0 >= N_NODES) return;
    const int g = lane >> 4;
    const int r = lane & 15;

    short8v a[4];
    const unsigned short* arow = xb + (size_t)(row0 + r) * D_IN + g * 8;
    #pragma unroll
    for (int s = 0; s < 4; ++s)
        a[s] = *reinterpret_cast<const short8v*>(arow + 32 * s);

    #pragma unroll
    for (int t = 0; t < 16; ++t) {
        const unsigned short* brow = wt + (size_t)(t * 16 + r) * D_IN + g * 8;
        float4v acc = {0.f, 0.f, 0.f, 0.f};
        #pragma unroll
        for (int s = 0; s < 4; ++s) {
            short8v b = *reinterpret_cast<const short8v*>(brow + 32 * s);
            acc = __builtin_amdgcn_mfma_f32_16x16x32_bf16(a[s], b, acc, 0, 0, 0);
        }
        #pragma unroll
        for (int q = 0; q < 4; ++q) {
            __builtin_nontemporal_store(
                fmaxf(acc[q], 0.f),
                out + (size_t)(row0 + g * 4 + q) * D_OUT + t * 16 + r);
        }
    }
}

extern "C" void kernel_launch(void* const* d_in, const int* in_sizes, int n_in,
                              void* d_out, int out_size, void* d_ws, size_t ws_size,
                              hipStream_t stream) {
    const float* h  = (const float*)d_in[0];
    const int* esrc = (const int*)d_in[1];
    const int* edst = (const int*)d_in[2];
    const float* ew = (const float*)d_in[3];
    const float* Wn = (const float*)d_in[4];
    float* out = (float*)d_out;

    // workspace layout (byte offsets, all 256B-aligned where it matters)
    char* ws = (char*)d_ws;
    unsigned short* hb  = (unsigned short*)(ws);                // 12,800,000 B
    unsigned short* xb  = (unsigned short*)(ws + 12800000);     // 12,800,000 B
    unsigned short* wt  = (unsigned short*)(ws + 25600000);     //     65,536 B
    int*   cursor       = (int*)(ws + 25665536);                //    200,000 B
    unsigned* bkt       = (unsigned*)(ws + 25865536);           // 12,800,000 B
    // total 38,665,536 B

    prep_streams<<<NB_CONVH + NB_CONVW + NB_ZERO, 256, 0, stream>>>(h, hb, Wn, wt, (int4*)cursor);
    const int eblocks = (N_EDGES + 255) / 256;
    bucket_fill<<<eblocks, 256, 0, stream>>>(esrc, edst, ew, cursor, bkt);
    gather_nodes<<<(N_NODES + 3) / 4, 256, 0, stream>>>(hb, cursor, bkt, xb);
    gemm_mfma<<<(N_NODES + 63) / 64, 256, 0, stream>>>(xb, wt, out);
}